// Round 1
// baseline (577.699 us; speedup 1.0000x reference)
//
#include <hip/hip_runtime.h>
#include <math.h>

#define BATCH 4
#define CCH   64
#define OCH   64
#define HH    128
#define WW    128
#define PCH   27     // 3*KK
#define HW    (HH*WW)

// ---------------------------------------------------------------------------
// Kernel 1: params = conv2d(x, pg_weight, pg_bias, pad=1)
// thread per (b, p, h, w); idx = ((b*27+p)*128+h)*128+w
// ---------------------------------------------------------------------------
__global__ __launch_bounds__(256) void conv_params_kernel(
    const float* __restrict__ x, const float* __restrict__ pgw,
    const float* __restrict__ pgb, float* __restrict__ params)
{
    int idx = blockIdx.x * 256 + threadIdx.x;
    int w  = idx & 127;
    int h  = (idx >> 7) & 127;
    int bp = idx >> 14;
    int p  = bp % 27;
    int b  = bp / 27;

    float acc = pgb[p];
    const float* xb = x   + b * CCH * HW;
    const float* wb = pgw + p * CCH * 9;

    for (int c = 0; c < CCH; ++c) {
        const float* xc = xb + c * HW;
        const float* wc = wb + c * 9;
        #pragma unroll
        for (int ky = 0; ky < 3; ++ky) {
            int y = h + ky - 1;
            if (y < 0 || y >= HH) continue;
            const float* row = xc + y * WW;
            #pragma unroll
            for (int kx = 0; kx < 3; ++kx) {
                int xx = w + kx - 1;
                if (xx < 0 || xx >= WW) continue;
                acc = fmaf(row[xx], wc[ky * 3 + kx], acc);
            }
        }
    }
    params[idx] = acc;
}

// ---------------------------------------------------------------------------
// Kernel 2: bilinear sampling + einsum.
// Block = (b, h, 16-pixel w-tile), 256 threads.
//   phase 1: 144 threads -> per (pixel,tap) meta in LDS
//   phase 2: build s[j=c*9+k][p] (576 x 16 fp32) in LDS
//   phase 3: out[o][p] = sum_j W[o*576+j] * s[j][p]  (thread = (o, 4-pixel grp))
// ---------------------------------------------------------------------------
__global__ __launch_bounds__(256) void deform_kernel(
    const float* __restrict__ x, const float* __restrict__ weight,
    const float* __restrict__ params, float* __restrict__ out)
{
    int blk = blockIdx.x;
    int wt  = blk & 7;            // W/16 = 8 tiles
    int h   = (blk >> 3) & 127;
    int b   = blk >> 10;
    int w0  = wt * 16;
    int t   = threadIdx.x;

    __shared__ int   m_y0[144], m_y1[144], m_x0[144], m_x1[144];
    __shared__ float m_w00[144], m_w01[144], m_w10[144], m_w11[144];
    __shared__ float s_lds[576 * 16];   // 36 KB

    if (t < 144) {
        int p  = t / 9;           // pixel in tile
        int k  = t - p * 9;       // tap
        int pw = w0 + p;
        const float* pp = params + b * PCH * HW + h * WW + pw;
        float dy = pp[(2 * k)     * HW];
        float dx = pp[(2 * k + 1) * HW];
        float mm = pp[(18 + k)    * HW];
        float mask = 1.0f / (1.0f + __expf(-mm));

        float py = (float)h  - 1.0f + (float)(k / 3) + dy;
        float px = (float)pw - 1.0f + (float)(k % 3) + dx;
        float y0f = floorf(py), x0f = floorf(px);
        float ly = py - y0f, lx = px - x0f;
        int y0 = (int)y0f, x0 = (int)x0f;
        int y1 = y0 + 1,   x1 = x0 + 1;

        float vy0 = (y0 >= 0 && y0 < HH) ? 1.0f : 0.0f;
        float vy1 = (y1 >= 0 && y1 < HH) ? 1.0f : 0.0f;
        float vx0 = (x0 >= 0 && x0 < WW) ? 1.0f : 0.0f;
        float vx1 = (x1 >= 0 && x1 < WW) ? 1.0f : 0.0f;

        m_w00[t] = (1.0f - ly) * (1.0f - lx) * mask * vy0 * vx0;
        m_w01[t] = (1.0f - ly) * lx          * mask * vy0 * vx1;
        m_w10[t] = ly * (1.0f - lx)          * mask * vy1 * vx0;
        m_w11[t] = ly * lx                   * mask * vy1 * vx1;
        m_y0[t] = min(max(y0, 0), HH - 1);
        m_y1[t] = min(max(y1, 0), HH - 1);
        m_x0[t] = min(max(x0, 0), WW - 1);
        m_x1[t] = min(max(x1, 0), WW - 1);
    }
    __syncthreads();

    // phase 2: 576*16 / 256 = 36 samples per thread
    const float* xb = x + b * CCH * HW;
    #pragma unroll 4
    for (int it = 0; it < 36; ++it) {
        int ss = t + it * 256;    // ss = j*16 + p
        int p  = ss & 15;
        int j  = ss >> 4;
        int c  = j / 9;
        int k  = j - c * 9;
        int mi = p * 9 + k;
        const float* xc = xb + c * HW;
        int y0 = m_y0[mi], y1 = m_y1[mi], x0 = m_x0[mi], x1 = m_x1[mi];
        float v = m_w00[mi] * xc[y0 * WW + x0]
                + m_w01[mi] * xc[y0 * WW + x1]
                + m_w10[mi] * xc[y1 * WW + x0]
                + m_w11[mi] * xc[y1 * WW + x1];
        s_lds[ss] = v;
    }
    __syncthreads();

    // phase 3: thread t -> o = t>>2, pixel group pg = t&3 (4 pixels)
    int o  = t >> 2;
    int pg = t & 3;
    float4 acc = make_float4(0.f, 0.f, 0.f, 0.f);
    const float*  wrow = weight + o * 576;
    const float4* sp   = (const float4*)s_lds + pg;   // s[j*16 + pg*4 .. +3]
    for (int j = 0; j < 576; ++j) {
        float  wv = wrow[j];
        float4 s4 = sp[j * 4];
        acc.x = fmaf(wv, s4.x, acc.x);
        acc.y = fmaf(wv, s4.y, acc.y);
        acc.z = fmaf(wv, s4.z, acc.z);
        acc.w = fmaf(wv, s4.w, acc.w);
    }
    float* op = out + ((b * OCH + o) * HH + h) * WW + w0 + pg * 4;
    *(float4*)op = acc;
}

// ---------------------------------------------------------------------------
extern "C" void kernel_launch(void* const* d_in, const int* in_sizes, int n_in,
                              void* d_out, int out_size, void* d_ws, size_t ws_size,
                              hipStream_t stream) {
    const float* x       = (const float*)d_in[0];
    const float* weight  = (const float*)d_in[1];
    const float* pgw     = (const float*)d_in[2];
    const float* pgb     = (const float*)d_in[3];
    float* out    = (float*)d_out;
    float* params = (float*)d_ws;            // B*27*H*W fp32 = 7.08 MB

    int n_params = BATCH * PCH * HW;         // 1,769,472
    conv_params_kernel<<<n_params / 256, 256, 0, stream>>>(x, pgw, pgb, params);

    int n_blocks = BATCH * HH * (WW / 16);   // 4096
    deform_kernel<<<n_blocks, 256, 0, stream>>>(x, weight, params, out);
}

// Round 5
// 358.077 us; speedup vs baseline: 1.6133x; 1.6133x over previous
//
#include <hip/hip_runtime.h>
#include <math.h>

#define BATCH 4
#define CCH   64
#define OCH   64
#define HH    128
#define WW    128
#define PCH   27     // 3*KK
#define HW    (HH*WW)

#define CCHUNK 16
#define NCHUNK (CCH/CCHUNK)

// ---------------------------------------------------------------------------
// Kernel 1 v2: params = conv2d(x, pg_weight, pg_bias, pad=1), LDS-tiled.
// Block = (b, h-row), 128 threads (one per w). 27 register accumulators.
// (UNCHANGED from round 1 — prediction still untested due to broker timeouts)
// ---------------------------------------------------------------------------
__global__ __launch_bounds__(128) void conv_params_v2(
    const float* __restrict__ x, const float* __restrict__ pgw,
    const float* __restrict__ pgb, float* __restrict__ params)
{
    __shared__ float xs[CCHUNK][3][132];   // [c][row][1+w+pad], 25.3 KB
    __shared__ float ws[CCHUNK][9][28];    // [c][tap][p(pad to 28)], 16.1 KB

    int h0 = blockIdx.x;           // 0..127
    int b  = blockIdx.y;           // 0..3
    int t  = threadIdx.x;          // 0..127
    int w  = t;

    // zero the pad columns once (positions 0,129,130,131 of each [c][row])
    for (int li = t; li < CCHUNK * 3 * 4; li += 128) {
        int pi  = li & 3;
        int pos = (pi == 0) ? 0 : (128 + pi);
        int row = (li >> 2) % 3;
        int cl  = li / 12;
        xs[cl][row][pos] = 0.0f;
    }

    float acc[27];
    #pragma unroll
    for (int p = 0; p < 27; ++p) acc[p] = 0.0f;

    const float* xb = x + b * CCH * HW;

    for (int cc = 0; cc < NCHUNK; ++cc) {
        int c0 = cc * CCHUNK;
        __syncthreads();
        // stage x: 16c x 3rows x 128w = 1536 float4s, 12 per thread
        #pragma unroll
        for (int i = 0; i < 12; ++i) {
            int li  = t + i * 128;
            int wq  = li & 31;
            int tmp = li >> 5;        // 0..47
            int row = tmp % 3;
            int cl  = tmp / 3;
            int hy  = h0 - 1 + row;
            float4 v = make_float4(0.f, 0.f, 0.f, 0.f);
            if (hy >= 0 && hy < HH)
                v = *(const float4*)(xb + (c0 + cl) * HW + hy * WW + wq * 4);
            float* d = &xs[cl][row][1 + wq * 4];
            d[0] = v.x; d[1] = v.y; d[2] = v.z; d[3] = v.w;
        }
        // stage weights: 16c x 9tap x 27p = 3888 scalars
        for (int li = t; li < CCHUNK * 9 * 27; li += 128) {
            int p   = li % 27;
            int tap = (li / 27) % 9;
            int cl  = li / 243;
            ws[cl][tap][p] = pgw[p * (CCH * 9) + (c0 + cl) * 9 + tap];
        }
        __syncthreads();

        for (int c = 0; c < CCHUNK; ++c) {
            #pragma unroll
            for (int ky = 0; ky < 3; ++ky) {
                #pragma unroll
                for (int kx = 0; kx < 3; ++kx) {
                    float xv  = xs[c][ky][w + kx];   // (w-1+kx) + 1 pad offset
                    int   tap = ky * 3 + kx;
                    #pragma unroll
                    for (int q = 0; q < 6; ++q) {
                        float4 wv = *(const float4*)&ws[c][tap][q * 4];
                        acc[q * 4 + 0] = fmaf(xv, wv.x, acc[q * 4 + 0]);
                        acc[q * 4 + 1] = fmaf(xv, wv.y, acc[q * 4 + 1]);
                        acc[q * 4 + 2] = fmaf(xv, wv.z, acc[q * 4 + 2]);
                        acc[q * 4 + 3] = fmaf(xv, wv.w, acc[q * 4 + 3]);
                    }
                    #pragma unroll
                    for (int p = 24; p < 27; ++p)
                        acc[p] = fmaf(xv, ws[c][tap][p], acc[p]);
                }
            }
        }
    }

    float* op = params + b * PCH * HW + h0 * WW + w;
    #pragma unroll
    for (int p = 0; p < 27; ++p)
        op[p * HW] = acc[p] + pgb[p];
}

// ---------------------------------------------------------------------------
// Kernel 2 v2: bilinear sampling + einsum.
// Change vs round 0: phase 3 j-loop unrolled x4 with float4 weight loads
// (4x fewer weight-load instructions, 16B/lane, 4-deep scheduling window).
// ---------------------------------------------------------------------------
__global__ __launch_bounds__(256) void deform_kernel(
    const float* __restrict__ x, const float* __restrict__ weight,
    const float* __restrict__ params, float* __restrict__ out)
{
    int blk = blockIdx.x;
    int wt  = blk & 7;            // W/16 = 8 tiles
    int h   = (blk >> 3) & 127;
    int b   = blk >> 10;
    int w0  = wt * 16;
    int t   = threadIdx.x;

    __shared__ int   m_y0[144], m_y1[144], m_x0[144], m_x1[144];
    __shared__ float m_w00[144], m_w01[144], m_w10[144], m_w11[144];
    __shared__ float s_lds[576 * 16];   // 36 KB

    if (t < 144) {
        int p  = t / 9;           // pixel in tile
        int k  = t - p * 9;       // tap
        int pw = w0 + p;
        const float* pp = params + b * PCH * HW + h * WW + pw;
        float dy = pp[(2 * k)     * HW];
        float dx = pp[(2 * k + 1) * HW];
        float mm = pp[(18 + k)    * HW];
        float mask = 1.0f / (1.0f + __expf(-mm));

        float py = (float)h  - 1.0f + (float)(k / 3) + dy;
        float px = (float)pw - 1.0f + (float)(k % 3) + dx;
        float y0f = floorf(py), x0f = floorf(px);
        float ly = py - y0f, lx = px - x0f;
        int y0 = (int)y0f, x0 = (int)x0f;
        int y1 = y0 + 1,   x1 = x0 + 1;

        float vy0 = (y0 >= 0 && y0 < HH) ? 1.0f : 0.0f;
        float vy1 = (y1 >= 0 && y1 < HH) ? 1.0f : 0.0f;
        float vx0 = (x0 >= 0 && x0 < WW) ? 1.0f : 0.0f;
        float vx1 = (x1 >= 0 && x1 < WW) ? 1.0f : 0.0f;

        m_w00[t] = (1.0f - ly) * (1.0f - lx) * mask * vy0 * vx0;
        m_w01[t] = (1.0f - ly) * lx          * mask * vy0 * vx1;
        m_w10[t] = ly * (1.0f - lx)          * mask * vy1 * vx0;
        m_w11[t] = ly * lx                   * mask * vy1 * vx1;
        m_y0[t] = min(max(y0, 0), HH - 1);
        m_y1[t] = min(max(y1, 0), HH - 1);
        m_x0[t] = min(max(x0, 0), WW - 1);
        m_x1[t] = min(max(x1, 0), WW - 1);
    }
    __syncthreads();

    // phase 2: 576*16 / 256 = 36 samples per thread
    const float* xb = x + b * CCH * HW;
    #pragma unroll 4
    for (int it = 0; it < 36; ++it) {
        int ss = t + it * 256;    // ss = j*16 + p
        int p  = ss & 15;
        int j  = ss >> 4;
        int c  = j / 9;
        int k  = j - c * 9;
        int mi = p * 9 + k;
        const float* xc = xb + c * HW;
        int y0 = m_y0[mi], y1 = m_y1[mi], x0 = m_x0[mi], x1 = m_x1[mi];
        float v = m_w00[mi] * xc[y0 * WW + x0]
                + m_w01[mi] * xc[y0 * WW + x1]
                + m_w10[mi] * xc[y1 * WW + x0]
                + m_w11[mi] * xc[y1 * WW + x1];
        s_lds[ss] = v;
    }
    __syncthreads();

    // phase 3: thread t -> o = t>>2, pixel group pg = t&3 (4 pixels)
    // j unrolled x4: one float4 weight load feeds 16 FMAs.
    int o  = t >> 2;
    int pg = t & 3;
    float4 acc = make_float4(0.f, 0.f, 0.f, 0.f);
    const float*  wrow = weight + o * 576;
    const float4* sp   = (const float4*)s_lds + pg;   // s[j*16 + pg*4 .. +3]
    #pragma unroll 2
    for (int j4 = 0; j4 < 144; ++j4) {
        float4 wv = *(const float4*)(wrow + j4 * 4);
        float4 s0 = sp[(j4 * 4 + 0) * 4];
        float4 s1 = sp[(j4 * 4 + 1) * 4];
        float4 s2 = sp[(j4 * 4 + 2) * 4];
        float4 s3 = sp[(j4 * 4 + 3) * 4];
        acc.x = fmaf(wv.x, s0.x, acc.x);
        acc.y = fmaf(wv.x, s0.y, acc.y);
        acc.z = fmaf(wv.x, s0.z, acc.z);
        acc.w = fmaf(wv.x, s0.w, acc.w);
        acc.x = fmaf(wv.y, s1.x, acc.x);
        acc.y = fmaf(wv.y, s1.y, acc.y);
        acc.z = fmaf(wv.y, s1.z, acc.z);
        acc.w = fmaf(wv.y, s1.w, acc.w);
        acc.x = fmaf(wv.z, s2.x, acc.x);
        acc.y = fmaf(wv.z, s2.y, acc.y);
        acc.z = fmaf(wv.z, s2.z, acc.z);
        acc.w = fmaf(wv.z, s2.w, acc.w);
        acc.x = fmaf(wv.w, s3.x, acc.x);
        acc.y = fmaf(wv.w, s3.y, acc.y);
        acc.z = fmaf(wv.w, s3.z, acc.z);
        acc.w = fmaf(wv.w, s3.w, acc.w);
    }
    float* op = out + ((b * OCH + o) * HH + h) * WW + w0 + pg * 4;
    *(float4*)op = acc;
}

// ---------------------------------------------------------------------------
extern "C" void kernel_launch(void* const* d_in, const int* in_sizes, int n_in,
                              void* d_out, int out_size, void* d_ws, size_t ws_size,
                              hipStream_t stream) {
    const float* x       = (const float*)d_in[0];
    const float* weight  = (const float*)d_in[1];
    const float* pgw     = (const float*)d_in[2];
    const float* pgb     = (const float*)d_in[3];
    float* out    = (float*)d_out;
    float* params = (float*)d_ws;            // B*27*H*W fp32 = 7.08 MB

    dim3 g1(HH, BATCH);                      // 512 blocks
    conv_params_v2<<<g1, 128, 0, stream>>>(x, pgw, pgb, params);

    int n_blocks = BATCH * HH * (WW / 16);   // 4096
    deform_kernel<<<n_blocks, 256, 0, stream>>>(x, weight, params, out);
}

// Round 6
// 267.313 us; speedup vs baseline: 2.1611x; 1.3395x over previous
//
#include <hip/hip_runtime.h>
#include <math.h>

#define BATCH 4
#define CCH   64
#define OCH   64
#define HH    128
#define WW    128
#define PCH   27     // 3*KK
#define HW    (HH*WW)

#define PTILE 32                 // pixels per block
#define SROW  584                // 576 + 8 bf16 pad -> 1168 B row, 16B aligned
#define KSTEPS 18                // 576 / 32

typedef __attribute__((ext_vector_type(8))) short bf16x8;
typedef __attribute__((ext_vector_type(4))) float f32x4;

static __device__ inline unsigned short f2bf(float f) {
    union { float f; unsigned u; } v; v.f = f;
    unsigned r = (v.u + 0x7FFFu + ((v.u >> 16) & 1u)) >> 16;   // RNE
    return (unsigned short)r;
}

// ---------------------------------------------------------------------------
// Kernel 0: convert weights to bf16 scratch.
//   Wpb[32][576]  <- pg_weight (27 rows, rows 27..31 zero)
//   Wb [64][576]  <- weight
// ---------------------------------------------------------------------------
__global__ __launch_bounds__(256) void convert_weights(
    const float* __restrict__ weight, const float* __restrict__ pgw,
    unsigned short* __restrict__ Wpb, unsigned short* __restrict__ Wb)
{
    int row = blockIdx.x;                       // 0..95
    if (row < 32) {
        for (int j = threadIdx.x; j < 576; j += 256)
            Wpb[row * 576 + j] = (row < PCH) ? f2bf(pgw[row * 576 + j]) : 0;
    } else {
        int r = row - 32;
        for (int j = threadIdx.x; j < 576; j += 256)
            Wb[r * 576 + j] = f2bf(weight[r * 576 + j]);
    }
}

// ---------------------------------------------------------------------------
// Kernel 1 v3: params conv as MFMA GEMM.
//   im2col B-tile [32 pix][576 j] bf16 in LDS (direct global gather),
//   A = Wpb (32x576, padded), 4 waves -> 4 output tiles (2 o x 2 p), K=576.
// ---------------------------------------------------------------------------
__global__ __launch_bounds__(256) void conv_params_mfma(
    const float* __restrict__ x, const unsigned short* __restrict__ Wpb,
    const float* __restrict__ pgb, float* __restrict__ params)
{
    __shared__ unsigned short s_lds[PTILE][SROW];   // 37.4 KB

    int wt = blockIdx.x;            // 0..3
    int h  = blockIdx.y;            // 0..127
    int b  = blockIdx.z;            // 0..3
    int w0 = wt * PTILE;
    int t  = threadIdx.x;

    // phase A: im2col gather, 576*32/256 = 72 elements per thread
    const float* xb = x + b * CCH * HW;
    #pragma unroll 4
    for (int it = 0; it < 72; ++it) {
        int ss = t + it * 256;      // ss = j*32 + p
        int p  = ss & 31;
        int j  = ss >> 5;
        int c  = j / 9;
        int tap = j - c * 9;
        int ky = tap / 3;
        int kx = tap - ky * 3;
        int y  = h + ky - 1;
        int xc = w0 + p + kx - 1;
        float v = 0.0f;
        if ((unsigned)y < (unsigned)HH && (unsigned)xc < (unsigned)WW)
            v = xb[c * HW + y * WW + xc];
        s_lds[p][j] = f2bf(v);
    }
    __syncthreads();

    // phase B: MFMA. wave -> (o-tile, p-tile)
    int wv = t >> 6;
    int l  = t & 63;
    int lr = l & 15;
    int lk = l >> 4;
    int o0 = (wv & 1) * 16;
    int p0 = (wv >> 1) * 16;

    f32x4 acc = {0.f, 0.f, 0.f, 0.f};
    const unsigned short* arow = Wpb + (o0 + lr) * 576 + lk * 8;
    const unsigned short* brow = &s_lds[p0 + lr][lk * 8];
    #pragma unroll
    for (int kk = 0; kk < KSTEPS; ++kk) {
        bf16x8 a  = *(const bf16x8*)(arow + kk * 32);
        bf16x8 bb = *(const bf16x8*)(brow + kk * 32);
        acc = __builtin_amdgcn_mfma_f32_16x16x32_bf16(a, bb, acc, 0, 0, 0);
    }

    // epilogue: C/D layout col=lane&15 (pixel), row=(lane>>4)*4+r (o)
    #pragma unroll
    for (int r = 0; r < 4; ++r) {
        int o = o0 + lk * 4 + r;
        if (o < PCH)
            params[((b * PCH + o) * HH + h) * WW + w0 + p0 + lr] = acc[r] + pgb[o];
    }
}

// ---------------------------------------------------------------------------
// Kernel 2 v3: bilinear sampling (fp32) -> s[32 pix][576 j] bf16 in LDS,
// then MFMA einsum out[64][32] = Wb[64x576] * s.
// ---------------------------------------------------------------------------
__global__ __launch_bounds__(256) void deform_mfma(
    const float* __restrict__ x, const unsigned short* __restrict__ Wb,
    const float* __restrict__ params, float* __restrict__ out)
{
    __shared__ unsigned short s_lds[PTILE][SROW];   // 37.4 KB
    __shared__ int   m_y0[288], m_y1[288], m_x0[288], m_x1[288];
    __shared__ float m_w00[288], m_w01[288], m_w10[288], m_w11[288];  // +9.2 KB

    int wt = blockIdx.x;            // 0..3
    int h  = blockIdx.y;            // 0..127
    int b  = blockIdx.z;            // 0..3
    int w0 = wt * PTILE;
    int t  = threadIdx.x;

    // phase 1: per (pixel, tap) bilinear meta (32*9 = 288 entries)
    for (int mi = t; mi < PTILE * 9; mi += 256) {
        int p  = mi / 9;
        int k  = mi - p * 9;
        int pw = w0 + p;
        const float* pp = params + b * PCH * HW + h * WW + pw;
        float dy = pp[(2 * k)     * HW];
        float dx = pp[(2 * k + 1) * HW];
        float mm = pp[(18 + k)    * HW];
        float mask = 1.0f / (1.0f + __expf(-mm));

        float py = (float)h  - 1.0f + (float)(k / 3) + dy;
        float px = (float)pw - 1.0f + (float)(k % 3) + dx;
        float y0f = floorf(py), x0f = floorf(px);
        float ly = py - y0f, lx = px - x0f;
        int y0 = (int)y0f, x0 = (int)x0f;
        int y1 = y0 + 1,   x1 = x0 + 1;

        float vy0 = (y0 >= 0 && y0 < HH) ? 1.0f : 0.0f;
        float vy1 = (y1 >= 0 && y1 < HH) ? 1.0f : 0.0f;
        float vx0 = (x0 >= 0 && x0 < WW) ? 1.0f : 0.0f;
        float vx1 = (x1 >= 0 && x1 < WW) ? 1.0f : 0.0f;

        m_w00[mi] = (1.0f - ly) * (1.0f - lx) * mask * vy0 * vx0;
        m_w01[mi] = (1.0f - ly) * lx          * mask * vy0 * vx1;
        m_w10[mi] = ly * (1.0f - lx)          * mask * vy1 * vx0;
        m_w11[mi] = ly * lx                   * mask * vy1 * vx1;
        m_y0[mi] = min(max(y0, 0), HH - 1);
        m_y1[mi] = min(max(y1, 0), HH - 1);
        m_x0[mi] = min(max(x0, 0), WW - 1);
        m_x1[mi] = min(max(x1, 0), WW - 1);
    }
    __syncthreads();

    // phase 2: sample 576*32/256 = 72 per thread, write bf16 to s_lds[p][j]
    const float* xb = x + b * CCH * HW;
    #pragma unroll 4
    for (int it = 0; it < 72; ++it) {
        int ss = t + it * 256;      // ss = j*32 + p
        int p  = ss & 31;
        int j  = ss >> 5;
        int c  = j / 9;
        int k  = j - c * 9;
        int mi = p * 9 + k;
        const float* xc = xb + c * HW;
        int y0 = m_y0[mi], y1 = m_y1[mi], x0 = m_x0[mi], x1 = m_x1[mi];
        float v = m_w00[mi] * xc[y0 * WW + x0]
                + m_w01[mi] * xc[y0 * WW + x1]
                + m_w10[mi] * xc[y1 * WW + x0]
                + m_w11[mi] * xc[y1 * WW + x1];
        s_lds[p][j] = f2bf(v);
    }
    __syncthreads();

    // phase 3: MFMA. wave wv -> o-tile o0 = wv*16, both p-tiles (0,16). K=576.
    int wv = t >> 6;
    int l  = t & 63;
    int lr = l & 15;
    int lk = l >> 4;
    int o0 = wv * 16;

    f32x4 acc0 = {0.f, 0.f, 0.f, 0.f};
    f32x4 acc1 = {0.f, 0.f, 0.f, 0.f};
    const unsigned short* arow = Wb + (o0 + lr) * 576 + lk * 8;
    const unsigned short* b0r  = &s_lds[lr][lk * 8];
    const unsigned short* b1r  = &s_lds[16 + lr][lk * 8];
    #pragma unroll
    for (int kk = 0; kk < KSTEPS; ++kk) {
        bf16x8 a  = *(const bf16x8*)(arow + kk * 32);
        bf16x8 b0 = *(const bf16x8*)(b0r + kk * 32);
        bf16x8 b1 = *(const bf16x8*)(b1r + kk * 32);
        acc0 = __builtin_amdgcn_mfma_f32_16x16x32_bf16(a, b0, acc0, 0, 0, 0);
        acc1 = __builtin_amdgcn_mfma_f32_16x16x32_bf16(a, b1, acc1, 0, 0, 0);
    }

    // epilogue: col=lane&15 (pixel), row=(lane>>4)*4+r (o)
    float* ob = out + ((long)(b * OCH) * HH + h) * WW + w0;
    #pragma unroll
    for (int r = 0; r < 4; ++r) {
        int o = o0 + lk * 4 + r;
        ob[(long)o * HW + lr]      = acc0[r];
        ob[(long)o * HW + 16 + lr] = acc1[r];
    }
}

// ---------------------------------------------------------------------------
extern "C" void kernel_launch(void* const* d_in, const int* in_sizes, int n_in,
                              void* d_out, int out_size, void* d_ws, size_t ws_size,
                              hipStream_t stream) {
    const float* x       = (const float*)d_in[0];
    const float* weight  = (const float*)d_in[1];
    const float* pgw     = (const float*)d_in[2];
    const float* pgb     = (const float*)d_in[3];
    float* out = (float*)d_out;

    // ws layout: params (B*27*HW f32 = 28,311,552 B) | Wpb (32x576 bf16) | Wb (64x576 bf16)
    float* params = (float*)d_ws;
    unsigned short* Wpb = (unsigned short*)(params + (size_t)BATCH * PCH * HW);
    unsigned short* Wb  = Wpb + 32 * 576;

    convert_weights<<<96, 256, 0, stream>>>(weight, pgw, Wpb, Wb);

    dim3 grid(WW / PTILE, HH, BATCH);          // 4 x 128 x 4 = 2048 blocks
    conv_params_mfma<<<grid, 256, 0, stream>>>(x, Wpb, pgb, params);
    deform_mfma<<<grid, 256, 0, stream>>>(x, Wb, params, out);
}

// Round 12
// 232.542 us; speedup vs baseline: 2.4843x; 1.1495x over previous
//
#include <hip/hip_runtime.h>
#include <math.h>

#define BATCH 4
#define CCH   64
#define OCH   64
#define HH    128
#define WW    128
#define PCH   27     // 3*KK
#define HW    (HH*WW)

#define PTILE 32                 // pixels per block
#define SROW  584                // s row stride in elements (1168 B, 16B-mult)
#define SXP   72                 // x-tile c-dim stride (144 B, 16B-mult)

typedef __attribute__((ext_vector_type(8))) short bf16x8;
typedef __attribute__((ext_vector_type(4))) float f32x4;

static __device__ inline unsigned short f2bf(float f) {
    union { float f; unsigned u; } v; v.f = f;
    unsigned r = (v.u + 0x7FFFu + ((v.u >> 16) & 1u)) >> 16;   // RNE
    return (unsigned short)r;
}

// ---------------------------------------------------------------------------
// Kernel 0: convert + reorder weights to bf16 scratch, tap-major K:
//   Wpb2[32][j2=tap*64+c] <- pg_weight[o][c][tap]   (rows 27..31 zero)
//   Wb2 [64][j2=tap*64+c] <- weight[o][c][tap]
// ---------------------------------------------------------------------------
__global__ __launch_bounds__(256) void convert_weights(
    const float* __restrict__ weight, const float* __restrict__ pgw,
    unsigned short* __restrict__ Wpb2, unsigned short* __restrict__ Wb2)
{
    int row = blockIdx.x;                       // 0..95
    if (row < 32) {
        for (int j = threadIdx.x; j < 576; j += 256) {
            int tap = j >> 6, c = j & 63;
            Wpb2[row * 576 + j] = (row < PCH) ? f2bf(pgw[row * 576 + c * 9 + tap]) : 0;
        }
    } else {
        int o = row - 32;
        for (int j = threadIdx.x; j < 576; j += 256) {
            int tap = j >> 6, c = j & 63;
            Wb2[o * 576 + j] = f2bf(weight[o * 576 + c * 9 + tap]);
        }
    }
}

// ---------------------------------------------------------------------------
// Fused kernel: params conv (MFMA) -> meta (regs) -> sampling -> einsum (MFMA)
// Block = (b, h, 32-pixel w-tile), 256 threads = 4 waves.
// ---------------------------------------------------------------------------
__global__ __launch_bounds__(256) void fused_deform(
    const float* __restrict__ x, const unsigned short* __restrict__ Wpb2,
    const unsigned short* __restrict__ Wb2, const float* __restrict__ pgb,
    float* __restrict__ out)
{
    __shared__ unsigned short s_lds[PTILE * SROW];   // 37376 B; aliased by x-tile in phase 1/2
    __shared__ float p_lds[PCH][PTILE];              // 3456 B

    int wt = blockIdx.x;            // 0..3
    int h  = blockIdx.y;            // 0..127
    int b  = blockIdx.z;            // 0..3
    int w0 = wt * PTILE;
    int t  = threadIdx.x;
    const float* xb = x + b * CCH * HW;

    // ---- phase 1: stage x rows h-1..h+1 into s_x[3][34][72] bf16 (aliases s_lds)
    unsigned short* s_x = s_lds;
    for (int li = t; li < 3 * 34 * 64; li += 256) {
        int px  = li % 34;
        int rc  = li / 34;          // 0..191
        int c   = rc & 63;
        int row = rc >> 6;
        int y   = h - 1 + row;
        int xg  = w0 - 1 + px;
        float v = 0.0f;
        if ((unsigned)y < (unsigned)HH && (unsigned)xg < (unsigned)WW)
            v = xb[c * HW + y * WW + xg];
        s_x[(row * 34 + px) * SXP + c] = f2bf(v);
    }
    __syncthreads();

    // ---- phase 2: params conv MFMA -> p_lds (+bias)
    int wv = t >> 6;
    int l  = t & 63;
    int lr = l & 15;
    int lk = l >> 4;
    {
        int o0 = (wv & 1) * 16;
        int p0 = (wv >> 1) * 16;
        f32x4 acc = {0.f, 0.f, 0.f, 0.f};
        const unsigned short* arow = Wpb2 + (o0 + lr) * 576 + lk * 8;
        #pragma unroll
        for (int tap = 0; tap < 9; ++tap) {
            int ky = tap / 3, kx = tap % 3;
            const unsigned short* bx = s_x + (ky * 34 + p0 + lr + kx) * SXP + lk * 8;
            bf16x8 a0 = *(const bf16x8*)(arow + tap * 64);
            bf16x8 b0 = *(const bf16x8*)(bx);
            acc = __builtin_amdgcn_mfma_f32_16x16x32_bf16(a0, b0, acc, 0, 0, 0);
            bf16x8 a1 = *(const bf16x8*)(arow + tap * 64 + 32);
            bf16x8 b1 = *(const bf16x8*)(bx + 32);
            acc = __builtin_amdgcn_mfma_f32_16x16x32_bf16(a1, b1, acc, 0, 0, 0);
        }
        #pragma unroll
        for (int r = 0; r < 4; ++r) {
            int o = o0 + lk * 4 + r;
            if (o < PCH)
                p_lds[o][p0 + lr] = acc[r] + pgb[o];
        }
    }
    __syncthreads();

    // ---- phase 3: per-thread meta (registers) + sampling, 1 b128 write per tap
    {
        int p  = t & 31;            // this thread's pixel
        int g  = t >> 5;            // c-group: channels g*8 .. g*8+7
        int pw = w0 + p;
        const float* xc0 = xb + (g * 8) * HW;

        #pragma unroll 1
        for (int k = 0; k < 9; ++k) {
            float dy = p_lds[2 * k][p];
            float dx = p_lds[2 * k + 1][p];
            float mm = p_lds[18 + k][p];
            float mask = 1.0f / (1.0f + __expf(-mm));

            float py  = (float)h  - 1.0f + (float)(k / 3) + dy;
            float pxf = (float)pw - 1.0f + (float)(k % 3) + dx;
            float y0f = floorf(py), x0f = floorf(pxf);
            float ly = py - y0f, lx = pxf - x0f;
            int y0 = (int)y0f, x0i = (int)x0f;
            int y1 = y0 + 1,   x1i = x0i + 1;

            float vy0 = ((unsigned)y0  < (unsigned)HH) ? 1.0f : 0.0f;
            float vy1 = ((unsigned)y1  < (unsigned)HH) ? 1.0f : 0.0f;
            float vx0 = ((unsigned)x0i < (unsigned)WW) ? 1.0f : 0.0f;
            float vx1 = ((unsigned)x1i < (unsigned)WW) ? 1.0f : 0.0f;

            float w00 = (1.0f - ly) * (1.0f - lx) * mask * vy0 * vx0;
            float w01 = (1.0f - ly) * lx          * mask * vy0 * vx1;
            float w10 = ly * (1.0f - lx)          * mask * vy1 * vx0;
            float w11 = ly * lx                   * mask * vy1 * vx1;

            int cy0 = min(max(y0, 0), HH - 1) * WW;
            int cy1 = min(max(y1, 0), HH - 1) * WW;
            int cx0 = min(max(x0i, 0), WW - 1);
            int cx1 = min(max(x1i, 0), WW - 1);

            bf16x8 pack;
            #pragma unroll
            for (int ci = 0; ci < 8; ++ci) {
                const float* xp = xc0 + ci * HW;
                float v = w00 * xp[cy0 + cx0] + w01 * xp[cy0 + cx1]
                        + w10 * xp[cy1 + cx0] + w11 * xp[cy1 + cx1];
                pack[ci] = (short)f2bf(v);
            }
            *(bf16x8*)&s_lds[p * SROW + k * 64 + g * 8] = pack;
        }
    }
    __syncthreads();

    // ---- phase 4: einsum MFMA out[64][32] = Wb2 * s
    {
        int o0 = wv * 16;
        f32x4 acc0 = {0.f, 0.f, 0.f, 0.f};
        f32x4 acc1 = {0.f, 0.f, 0.f, 0.f};
        const unsigned short* arow = Wb2 + (o0 + lr) * 576 + lk * 8;
        const unsigned short* b0r  = &s_lds[lr * SROW + lk * 8];
        const unsigned short* b1r  = &s_lds[(16 + lr) * SROW + lk * 8];
        #pragma unroll
        for (int kk = 0; kk < 18; ++kk) {
            bf16x8 a  = *(const bf16x8*)(arow + kk * 32);
            bf16x8 b0 = *(const bf16x8*)(b0r + kk * 32);
            bf16x8 b1 = *(const bf16x8*)(b1r + kk * 32);
            acc0 = __builtin_amdgcn_mfma_f32_16x16x32_bf16(a, b0, acc0, 0, 0, 0);
            acc1 = __builtin_amdgcn_mfma_f32_16x16x32_bf16(a, b1, acc1, 0, 0, 0);
        }
        float* ob = out + ((long)(b * OCH) * HH + h) * WW + w0;
        #pragma unroll
        for (int r = 0; r < 4; ++r) {
            int o = o0 + lk * 4 + r;
            ob[(long)o * HW + lr]      = acc0[r];
            ob[(long)o * HW + 16 + lr] = acc1[r];
        }
    }
}

// ---------------------------------------------------------------------------
extern "C" void kernel_launch(void* const* d_in, const int* in_sizes, int n_in,
                              void* d_out, int out_size, void* d_ws, size_t ws_size,
                              hipStream_t stream) {
    const float* x       = (const float*)d_in[0];
    const float* weight  = (const float*)d_in[1];
    const float* pgw     = (const float*)d_in[2];
    const float* pgb     = (const float*)d_in[3];
    float* out = (float*)d_out;

    // ws layout: Wpb2 (32x576 bf16) | Wb2 (64x576 bf16)  = 110 KB
    unsigned short* Wpb2 = (unsigned short*)d_ws;
    unsigned short* Wb2  = Wpb2 + 32 * 576;

    convert_weights<<<96, 256, 0, stream>>>(weight, pgw, Wpb2, Wb2);

    dim3 grid(WW / PTILE, HH, BATCH);          // 4 x 128 x 4 = 2048 blocks
    fused_deform<<<grid, 256, 0, stream>>>(x, Wpb2, Wb2, pgb, out);
}

// Round 13
// 151.815 us; speedup vs baseline: 3.8053x; 1.5317x over previous
//
#include <hip/hip_runtime.h>
#include <math.h>

#define BATCH 4
#define CCH   64
#define OCH   64
#define HH    128
#define WW    128
#define PCH   27     // 3*KK
#define HW    (HH*WW)

#define PTILE 32                 // pixels per block
#define SROW  584                // s row stride in elements (1168 B, 16B-mult)
#define SXP   72                 // x-tile c-dim stride (144 B, 16B-mult)

typedef __attribute__((ext_vector_type(8))) short bf16x8;
typedef __attribute__((ext_vector_type(4))) float f32x4;

static __device__ inline unsigned short f2bf(float f) {
    union { float f; unsigned u; } v; v.f = f;
    unsigned r = (v.u + 0x7FFFu + ((v.u >> 16) & 1u)) >> 16;   // RNE
    return (unsigned short)r;
}
static __device__ inline float bf2f(unsigned short u) {
    union { unsigned u; float f; } v; v.u = ((unsigned)u) << 16;
    return v.f;
}

// ---------------------------------------------------------------------------
// Kernel 0a: convert + reorder weights to bf16 scratch, tap-major K:
//   Wpb2[32][j2=tap*64+c] <- pg_weight[o][c][tap]   (rows 27..31 zero)
//   Wb2 [64][j2=tap*64+c] <- weight[o][c][tap]
// ---------------------------------------------------------------------------
__global__ __launch_bounds__(256) void convert_weights(
    const float* __restrict__ weight, const float* __restrict__ pgw,
    unsigned short* __restrict__ Wpb2, unsigned short* __restrict__ Wb2)
{
    int row = blockIdx.x;                       // 0..95
    if (row < 32) {
        for (int j = threadIdx.x; j < 576; j += 256) {
            int tap = j >> 6, c = j & 63;
            Wpb2[row * 576 + j] = (row < PCH) ? f2bf(pgw[row * 576 + c * 9 + tap]) : 0;
        }
    } else {
        int o = row - 32;
        for (int j = threadIdx.x; j < 576; j += 256) {
            int tap = j >> 6, c = j & 63;
            Wb2[o * 576 + j] = f2bf(weight[o * 576 + c * 9 + tap]);
        }
    }
}

// ---------------------------------------------------------------------------
// Kernel 0b: transpose x (NCHW fp32) -> xT[b][h][w][c] bf16 (channel-last).
// Block = (16-w chunk, h, b), 256 threads = 16c x 16w, 4 c-chunks.
// Reads: 16 c-lanes stride HW (each 64B line = exactly the 16-w chunk).
// Writes: 16 c-lanes contiguous 32B.
// ---------------------------------------------------------------------------
__global__ __launch_bounds__(256) void transpose_x(
    const float* __restrict__ x, unsigned short* __restrict__ xT)
{
    int wt = blockIdx.x;            // 0..7
    int h  = blockIdx.y;            // 0..127
    int b  = blockIdx.z;            // 0..3
    int t  = threadIdx.x;
    int cl = t & 15;                // c fastest -> coalesced writes
    int wl = t >> 4;                // 0..15
    int w  = wt * 16 + wl;

    const float* xb = x + (size_t)b * CCH * HW + h * WW + w;
    unsigned short* ob = xT + ((size_t)(b * HH + h) * WW + w) * 64;
    #pragma unroll
    for (int cc = 0; cc < 4; ++cc) {
        int c = cc * 16 + cl;
        ob[c] = f2bf(xb[(size_t)c * HW]);
    }
}

// ---------------------------------------------------------------------------
// Fused kernel: params conv (MFMA) -> meta (regs) -> sampling -> einsum (MFMA)
// Block = (b, h, 32-pixel w-tile), 256 threads = 4 waves.
// All x access now via channel-last bf16 xT (16B vector gathers).
// ---------------------------------------------------------------------------
__global__ __launch_bounds__(256) void fused_deform(
    const unsigned short* __restrict__ xT, const unsigned short* __restrict__ Wpb2,
    const unsigned short* __restrict__ Wb2, const float* __restrict__ pgb,
    float* __restrict__ out)
{
    __shared__ unsigned short s_lds[PTILE * SROW];   // 37376 B; aliased by x-tile in phase 1/2
    __shared__ float p_lds[PCH][PTILE];              // 3456 B

    int wt = blockIdx.x;            // 0..3
    int h  = blockIdx.y;            // 0..127
    int b  = blockIdx.z;            // 0..3
    int w0 = wt * PTILE;
    int t  = threadIdx.x;
    const unsigned short* xtb = xT + (size_t)b * HW * 64;

    // ---- phase 1: stage x rows h-1..h+1 into s_x[3][34][SXP] bf16 (aliases s_lds)
    unsigned short* s_x = s_lds;
    for (int li = t; li < 3 * 34 * 8; li += 256) {   // 816 x 16B chunks
        int cg  = li & 7;
        int px  = (li >> 3) % 34;
        int row = li / (34 * 8);
        int y   = h - 1 + row;
        int xg  = w0 - 1 + px;
        bf16x8 v = {0, 0, 0, 0, 0, 0, 0, 0};
        if ((unsigned)y < (unsigned)HH && (unsigned)xg < (unsigned)WW)
            v = *(const bf16x8*)(xtb + ((size_t)(y * WW + xg)) * 64 + cg * 8);
        *(bf16x8*)&s_x[(row * 34 + px) * SXP + cg * 8] = v;
    }
    __syncthreads();

    // ---- phase 2: params conv MFMA -> p_lds (+bias)
    int wv = t >> 6;
    int l  = t & 63;
    int lr = l & 15;
    int lk = l >> 4;
    {
        int o0 = (wv & 1) * 16;
        int p0 = (wv >> 1) * 16;
        f32x4 acc = {0.f, 0.f, 0.f, 0.f};
        const unsigned short* arow = Wpb2 + (o0 + lr) * 576 + lk * 8;
        #pragma unroll
        for (int tap = 0; tap < 9; ++tap) {
            int ky = tap / 3, kx = tap % 3;
            const unsigned short* bx = s_x + (ky * 34 + p0 + lr + kx) * SXP + lk * 8;
            bf16x8 a0 = *(const bf16x8*)(arow + tap * 64);
            bf16x8 b0 = *(const bf16x8*)(bx);
            acc = __builtin_amdgcn_mfma_f32_16x16x32_bf16(a0, b0, acc, 0, 0, 0);
            bf16x8 a1 = *(const bf16x8*)(arow + tap * 64 + 32);
            bf16x8 b1 = *(const bf16x8*)(bx + 32);
            acc = __builtin_amdgcn_mfma_f32_16x16x32_bf16(a1, b1, acc, 0, 0, 0);
        }
        #pragma unroll
        for (int r = 0; r < 4; ++r) {
            int o = o0 + lk * 4 + r;
            if (o < PCH)
                p_lds[o][p0 + lr] = acc[r] + pgb[o];
        }
    }
    __syncthreads();

    // ---- phase 3: per-thread meta (registers) + 16B-vector sampling
    {
        int p  = t & 31;            // this thread's pixel
        int g  = t >> 5;            // c-group: channels g*8 .. g*8+7
        int pw = w0 + p;
        const unsigned short* xg8 = xtb + g * 8;

        #pragma unroll 3
        for (int k = 0; k < 9; ++k) {
            float dy = p_lds[2 * k][p];
            float dx = p_lds[2 * k + 1][p];
            float mm = p_lds[18 + k][p];
            float mask = 1.0f / (1.0f + __expf(-mm));

            float py  = (float)h  - 1.0f + (float)(k / 3) + dy;
            float pxf = (float)pw - 1.0f + (float)(k % 3) + dx;
            float y0f = floorf(py), x0f = floorf(pxf);
            float ly = py - y0f, lx = pxf - x0f;
            int y0 = (int)y0f, x0i = (int)x0f;
            int y1 = y0 + 1,   x1i = x0i + 1;

            float vy0 = ((unsigned)y0  < (unsigned)HH) ? 1.0f : 0.0f;
            float vy1 = ((unsigned)y1  < (unsigned)HH) ? 1.0f : 0.0f;
            float vx0 = ((unsigned)x0i < (unsigned)WW) ? 1.0f : 0.0f;
            float vx1 = ((unsigned)x1i < (unsigned)WW) ? 1.0f : 0.0f;

            float w00 = (1.0f - ly) * (1.0f - lx) * mask * vy0 * vx0;
            float w01 = (1.0f - ly) * lx          * mask * vy0 * vx1;
            float w10 = ly * (1.0f - lx)          * mask * vy1 * vx0;
            float w11 = ly * lx                   * mask * vy1 * vx1;

            int cy0 = min(max(y0, 0), HH - 1) * WW;
            int cy1 = min(max(y1, 0), HH - 1) * WW;
            int cx0 = min(max(x0i, 0), WW - 1);
            int cx1 = min(max(x1i, 0), WW - 1);

            bf16x8 c00 = *(const bf16x8*)(xg8 + (size_t)(cy0 + cx0) * 64);
            bf16x8 c01 = *(const bf16x8*)(xg8 + (size_t)(cy0 + cx1) * 64);
            bf16x8 c10 = *(const bf16x8*)(xg8 + (size_t)(cy1 + cx0) * 64);
            bf16x8 c11 = *(const bf16x8*)(xg8 + (size_t)(cy1 + cx1) * 64);

            bf16x8 pack;
            #pragma unroll
            for (int ci = 0; ci < 8; ++ci) {
                float v = w00 * bf2f((unsigned short)c00[ci])
                        + w01 * bf2f((unsigned short)c01[ci])
                        + w10 * bf2f((unsigned short)c10[ci])
                        + w11 * bf2f((unsigned short)c11[ci]);
                pack[ci] = (short)f2bf(v);
            }
            *(bf16x8*)&s_lds[p * SROW + k * 64 + g * 8] = pack;
        }
    }
    __syncthreads();

    // ---- phase 4: einsum MFMA out[64][32] = Wb2 * s
    {
        int o0 = wv * 16;
        f32x4 acc0 = {0.f, 0.f, 0.f, 0.f};
        f32x4 acc1 = {0.f, 0.f, 0.f, 0.f};
        const unsigned short* arow = Wb2 + (o0 + lr) * 576 + lk * 8;
        const unsigned short* b0r  = &s_lds[lr * SROW + lk * 8];
        const unsigned short* b1r  = &s_lds[(16 + lr) * SROW + lk * 8];
        #pragma unroll
        for (int kk = 0; kk < 18; ++kk) {
            bf16x8 a  = *(const bf16x8*)(arow + kk * 32);
            bf16x8 b0 = *(const bf16x8*)(b0r + kk * 32);
            bf16x8 b1 = *(const bf16x8*)(b1r + kk * 32);
            acc0 = __builtin_amdgcn_mfma_f32_16x16x32_bf16(a, b0, acc0, 0, 0, 0);
            acc1 = __builtin_amdgcn_mfma_f32_16x16x32_bf16(a, b1, acc1, 0, 0, 0);
        }
        float* ob = out + ((long)(b * OCH) * HH + h) * WW + w0;
        #pragma unroll
        for (int r = 0; r < 4; ++r) {
            int o = o0 + lk * 4 + r;
            ob[(long)o * HW + lr]      = acc0[r];
            ob[(long)o * HW + 16 + lr] = acc1[r];
        }
    }
}

// ---------------------------------------------------------------------------
extern "C" void kernel_launch(void* const* d_in, const int* in_sizes, int n_in,
                              void* d_out, int out_size, void* d_ws, size_t ws_size,
                              hipStream_t stream) {
    const float* x       = (const float*)d_in[0];
    const float* weight  = (const float*)d_in[1];
    const float* pgw     = (const float*)d_in[2];
    const float* pgb     = (const float*)d_in[3];
    float* out = (float*)d_out;

    // ws layout: Wpb2 (32x576 bf16 = 36864B) | Wb2 (64x576 bf16 = 73728B)
    //          | xT (B*H*W*C bf16 = 8388608B)   -> total ~8.5 MB
    unsigned short* Wpb2 = (unsigned short*)d_ws;
    unsigned short* Wb2  = Wpb2 + 32 * 576;
    unsigned short* xTp  = Wb2 + 64 * 576;

    convert_weights<<<96, 256, 0, stream>>>(weight, pgw, Wpb2, Wb2);

    dim3 gt(WW / 16, HH, BATCH);               // 8 x 128 x 4 = 4096 blocks
    transpose_x<<<gt, 256, 0, stream>>>(x, xTp);

    dim3 grid(WW / PTILE, HH, BATCH);          // 4 x 128 x 4 = 2048 blocks
    fused_deform<<<grid, 256, 0, stream>>>(xTp, Wpb2, Wb2, pgb, out);
}

// Round 16
// 146.003 us; speedup vs baseline: 3.9568x; 1.0398x over previous
//
#include <hip/hip_runtime.h>
#include <math.h>

#define BATCH 4
#define CCH   64
#define OCH   64
#define HH    128
#define WW    128
#define PCH   27     // 3*KK
#define HW    (HH*WW)

#define PTILE 32                 // pixels per block
#define SROW  584                // s row stride in elements (1168 B, 16B-mult)
#define SXP   72                 // x-tile c-dim stride (144 B, 16B-mult)

typedef __attribute__((ext_vector_type(8))) short bf16x8;
typedef __attribute__((ext_vector_type(4))) float f32x4;

static __device__ inline unsigned short f2bf(float f) {
    union { float f; unsigned u; } v; v.f = f;
    unsigned r = (v.u + 0x7FFFu + ((v.u >> 16) & 1u)) >> 16;   // RNE
    return (unsigned short)r;
}
static __device__ inline float bf2f(unsigned short u) {
    union { unsigned u; float f; } v; v.u = ((unsigned)u) << 16;
    return v.f;
}

// ---------------------------------------------------------------------------
// Kernel 0a: convert + reorder weights to bf16 scratch, tap-major K:
//   Wpb2[32][j2=tap*64+c] <- pg_weight[o][c][tap]   (rows 27..31 zero)
//   Wb2 [64][j2=tap*64+c] <- weight[o][c][tap]
// ---------------------------------------------------------------------------
__global__ __launch_bounds__(256) void convert_weights(
    const float* __restrict__ weight, const float* __restrict__ pgw,
    unsigned short* __restrict__ Wpb2, unsigned short* __restrict__ Wb2)
{
    int row = blockIdx.x;                       // 0..95
    if (row < 32) {
        for (int j = threadIdx.x; j < 576; j += 256) {
            int tap = j >> 6, c = j & 63;
            Wpb2[row * 576 + j] = (row < PCH) ? f2bf(pgw[row * 576 + c * 9 + tap]) : 0;
        }
    } else {
        int o = row - 32;
        for (int j = threadIdx.x; j < 576; j += 256) {
            int tap = j >> 6, c = j & 63;
            Wb2[o * 576 + j] = f2bf(weight[o * 576 + c * 9 + tap]);
        }
    }
}

// ---------------------------------------------------------------------------
// Kernel 0b v2: LDS-staged transpose x (NCHW fp32) -> xT[b][h][w][c] bf16.
// Block = (h, b), 256 threads, one h-row (64c x 128w) per block.
//   read : lanes vary w  -> 256 B contiguous per instr (coalesced)
//   LDS  : tile[128][74] (stride 37 words, 5w mod 32 -> conflict-free)
//   write: lanes vary c  -> 128 B contiguous per instr (coalesced)
// ---------------------------------------------------------------------------
__global__ __launch_bounds__(256) void transpose_x(
    const float* __restrict__ x, unsigned short* __restrict__ xT)
{
    __shared__ unsigned short tile[128][74];   // 18944 B
    int h = blockIdx.x;
    int b = blockIdx.y;
    int t = threadIdx.x;

    const float* xb = x + (size_t)b * CCH * HW + h * WW;
    #pragma unroll
    for (int it = 0; it < 32; ++it) {
        int li = it * 256 + t;
        int w  = li & 127;
        int c  = li >> 7;
        tile[w][c] = f2bf(xb[(size_t)c * HW + w]);
    }
    __syncthreads();

    unsigned short* ob = xT + (size_t)(b * HH + h) * WW * 64;
    #pragma unroll
    for (int it = 0; it < 32; ++it) {
        int li = it * 256 + t;
        int c  = li & 63;
        int w  = li >> 6;
        ob[(size_t)w * 64 + c] = tile[w][c];
    }
}

// ---------------------------------------------------------------------------
// Fused kernel: params conv (MFMA) -> meta (regs) -> sampling -> einsum (MFMA)
// Block = (b, h, 32-pixel w-tile), 256 threads = 4 waves.
// All x access via channel-last bf16 xT (16B vector gathers).
// (UNCHANGED from round 12 for clean A/B.)
// ---------------------------------------------------------------------------
__global__ __launch_bounds__(256) void fused_deform(
    const unsigned short* __restrict__ xT, const unsigned short* __restrict__ Wpb2,
    const unsigned short* __restrict__ Wb2, const float* __restrict__ pgb,
    float* __restrict__ out)
{
    __shared__ unsigned short s_lds[PTILE * SROW];   // 37376 B; aliased by x-tile in phase 1/2
    __shared__ float p_lds[PCH][PTILE];              // 3456 B

    int wt = blockIdx.x;            // 0..3
    int h  = blockIdx.y;            // 0..127
    int b  = blockIdx.z;            // 0..3
    int w0 = wt * PTILE;
    int t  = threadIdx.x;
    const unsigned short* xtb = xT + (size_t)b * HW * 64;

    // ---- phase 1: stage x rows h-1..h+1 into s_x[3][34][SXP] bf16 (aliases s_lds)
    unsigned short* s_x = s_lds;
    for (int li = t; li < 3 * 34 * 8; li += 256) {   // 816 x 16B chunks
        int cg  = li & 7;
        int px  = (li >> 3) % 34;
        int row = li / (34 * 8);
        int y   = h - 1 + row;
        int xg  = w0 - 1 + px;
        bf16x8 v = {0, 0, 0, 0, 0, 0, 0, 0};
        if ((unsigned)y < (unsigned)HH && (unsigned)xg < (unsigned)WW)
            v = *(const bf16x8*)(xtb + ((size_t)(y * WW + xg)) * 64 + cg * 8);
        *(bf16x8*)&s_x[(row * 34 + px) * SXP + cg * 8] = v;
    }
    __syncthreads();

    // ---- phase 2: params conv MFMA -> p_lds (+bias)
    int wv = t >> 6;
    int l  = t & 63;
    int lr = l & 15;
    int lk = l >> 4;
    {
        int o0 = (wv & 1) * 16;
        int p0 = (wv >> 1) * 16;
        f32x4 acc = {0.f, 0.f, 0.f, 0.f};
        const unsigned short* arow = Wpb2 + (o0 + lr) * 576 + lk * 8;
        #pragma unroll
        for (int tap = 0; tap < 9; ++tap) {
            int ky = tap / 3, kx = tap % 3;
            const unsigned short* bx = s_x + (ky * 34 + p0 + lr + kx) * SXP + lk * 8;
            bf16x8 a0 = *(const bf16x8*)(arow + tap * 64);
            bf16x8 b0 = *(const bf16x8*)(bx);
            acc = __builtin_amdgcn_mfma_f32_16x16x32_bf16(a0, b0, acc, 0, 0, 0);
            bf16x8 a1 = *(const bf16x8*)(arow + tap * 64 + 32);
            bf16x8 b1 = *(const bf16x8*)(bx + 32);
            acc = __builtin_amdgcn_mfma_f32_16x16x32_bf16(a1, b1, acc, 0, 0, 0);
        }
        #pragma unroll
        for (int r = 0; r < 4; ++r) {
            int o = o0 + lk * 4 + r;
            if (o < PCH)
                p_lds[o][p0 + lr] = acc[r] + pgb[o];
        }
    }
    __syncthreads();

    // ---- phase 3: per-thread meta (registers) + 16B-vector sampling
    {
        int p  = t & 31;            // this thread's pixel
        int g  = t >> 5;            // c-group: channels g*8 .. g*8+7
        int pw = w0 + p;
        const unsigned short* xg8 = xtb + g * 8;

        #pragma unroll 3
        for (int k = 0; k < 9; ++k) {
            float dy = p_lds[2 * k][p];
            float dx = p_lds[2 * k + 1][p];
            float mm = p_lds[18 + k][p];
            float mask = 1.0f / (1.0f + __expf(-mm));

            float py  = (float)h  - 1.0f + (float)(k / 3) + dy;
            float pxf = (float)pw - 1.0f + (float)(k % 3) + dx;
            float y0f = floorf(py), x0f = floorf(pxf);
            float ly = py - y0f, lx = pxf - x0f;
            int y0 = (int)y0f, x0i = (int)x0f;
            int y1 = y0 + 1,   x1i = x0i + 1;

            float vy0 = ((unsigned)y0  < (unsigned)HH) ? 1.0f : 0.0f;
            float vy1 = ((unsigned)y1  < (unsigned)HH) ? 1.0f : 0.0f;
            float vx0 = ((unsigned)x0i < (unsigned)WW) ? 1.0f : 0.0f;
            float vx1 = ((unsigned)x1i < (unsigned)WW) ? 1.0f : 0.0f;

            float w00 = (1.0f - ly) * (1.0f - lx) * mask * vy0 * vx0;
            float w01 = (1.0f - ly) * lx          * mask * vy0 * vx1;
            float w10 = ly * (1.0f - lx)          * mask * vy1 * vx0;
            float w11 = ly * lx                   * mask * vy1 * vx1;

            int cy0 = min(max(y0, 0), HH - 1) * WW;
            int cy1 = min(max(y1, 0), HH - 1) * WW;
            int cx0 = min(max(x0i, 0), WW - 1);
            int cx1 = min(max(x1i, 0), WW - 1);

            bf16x8 c00 = *(const bf16x8*)(xg8 + (size_t)(cy0 + cx0) * 64);
            bf16x8 c01 = *(const bf16x8*)(xg8 + (size_t)(cy0 + cx1) * 64);
            bf16x8 c10 = *(const bf16x8*)(xg8 + (size_t)(cy1 + cx0) * 64);
            bf16x8 c11 = *(const bf16x8*)(xg8 + (size_t)(cy1 + cx1) * 64);

            bf16x8 pack;
            #pragma unroll
            for (int ci = 0; ci < 8; ++ci) {
                float v = w00 * bf2f((unsigned short)c00[ci])
                        + w01 * bf2f((unsigned short)c01[ci])
                        + w10 * bf2f((unsigned short)c10[ci])
                        + w11 * bf2f((unsigned short)c11[ci]);
                pack[ci] = (short)f2bf(v);
            }
            *(bf16x8*)&s_lds[p * SROW + k * 64 + g * 8] = pack;
        }
    }
    __syncthreads();

    // ---- phase 4: einsum MFMA out[64][32] = Wb2 * s
    {
        int o0 = wv * 16;
        f32x4 acc0 = {0.f, 0.f, 0.f, 0.f};
        f32x4 acc1 = {0.f, 0.f, 0.f, 0.f};
        const unsigned short* arow = Wb2 + (o0 + lr) * 576 + lk * 8;
        const unsigned short* b0r  = &s_lds[lr * SROW + lk * 8];
        const unsigned short* b1r  = &s_lds[(16 + lr) * SROW + lk * 8];
        #pragma unroll
        for (int kk = 0; kk < 18; ++kk) {
            bf16x8 a  = *(const bf16x8*)(arow + kk * 32);
            bf16x8 b0 = *(const bf16x8*)(b0r + kk * 32);
            bf16x8 b1 = *(const bf16x8*)(b1r + kk * 32);
            acc0 = __builtin_amdgcn_mfma_f32_16x16x32_bf16(a, b0, acc0, 0, 0, 0);
            acc1 = __builtin_amdgcn_mfma_f32_16x16x32_bf16(a, b1, acc1, 0, 0, 0);
        }
        float* ob = out + ((long)(b * OCH) * HH + h) * WW + w0;
        #pragma unroll
        for (int r = 0; r < 4; ++r) {
            int o = o0 + lk * 4 + r;
            ob[(long)o * HW + lr]      = acc0[r];
            ob[(long)o * HW + 16 + lr] = acc1[r];
        }
    }
}

// ---------------------------------------------------------------------------
extern "C" void kernel_launch(void* const* d_in, const int* in_sizes, int n_in,
                              void* d_out, int out_size, void* d_ws, size_t ws_size,
                              hipStream_t stream) {
    const float* x       = (const float*)d_in[0];
    const float* weight  = (const float*)d_in[1];
    const float* pgw     = (const float*)d_in[2];
    const float* pgb     = (const float*)d_in[3];
    float* out = (float*)d_out;

    // ws layout: Wpb2 (32x576 bf16 = 36864B) | Wb2 (64x576 bf16 = 73728B)
    //          | xT (B*H*W*C bf16 = 8388608B)   -> total ~8.5 MB
    unsigned short* Wpb2 = (unsigned short*)d_ws;
    unsigned short* Wb2  = Wpb2 + 32 * 576;
    unsigned short* xTp  = Wb2 + 64 * 576;

    convert_weights<<<96, 256, 0, stream>>>(weight, pgw, Wpb2, Wb2);

    dim3 gt(HH, BATCH);                        // 512 blocks
    transpose_x<<<gt, 256, 0, stream>>>(x, xTp);

    dim3 grid(WW / PTILE, HH, BATCH);          // 4 x 128 x 4 = 2048 blocks
    fused_deform<<<grid, 256, 0, stream>>>(xTp, Wpb2, Wb2, pgb, out);
}